// Round 10
// baseline (1522.036 us; speedup 1.0000x reference)
//
#include <hip/hip_runtime.h>

static constexpr int BB = 16;      // batches
static constexpr int NN = 325;     // nodes
static constexpr int DD = 64;      // channels
static constexpr int SEQ = 12;
static constexpr int MAXDEG = 80;  // per-row cap: Binom(324,0.1) mean 32.4, sd 5.4 -> 8.8 sigma
static constexpr int SLOTS = 21;   // node slots per block (16 blocks x 21 >= 325, round-robin dealt)
static constexpr int SLDS = 68;    // padded slab row stride (dwords); 68*4=272B = 17*16B
static constexpr int WPAD = 84;    // wbuf inner pad (84%32=20 -> conflict-free head rows)
static constexpr float DT = 0.1f;
static constexpr float NEG = 0.2f;
static constexpr float THRESH = 0.9f;

typedef float v4f __attribute__((ext_vector_type(4)));

__device__ __forceinline__ float rdl(float v, int sl) {
  return __int_as_float(__builtin_amdgcn_readlane(__float_as_int(v), sl));
}
// slab swizzle: dword offset within row for channel-quad q (0..15), row r
__device__ __forceinline__ int slab_off(int r, int q) {
  return r * SLDS + ((q ^ ((r >> 3) & 7)) << 2);
}

// ---- adjacency build: one wave per row, ballot compaction into padded u16 list
__global__ __launch_bounds__(64) void adj_k(const float* __restrict__ graph,
                                            int* __restrict__ deg,
                                            unsigned short* __restrict__ cols) {
  const int r = blockIdx.x;
  const int lane = threadIdx.x;
  int dc = 0;
  for (int base = 0; base < NN; base += 64) {
    int j = base + lane;
    bool pred = (j < NN) && ((graph[(size_t)r * NN + j] > THRESH) || (j == r));
    unsigned long long mk = __ballot(pred);
    int pos = dc + (int)__popcll(mk & ((1ULL << lane) - 1ULL));
    if (pred && pos < MAXDEG) cols[(size_t)r * MAXDEG + pos] = (unsigned short)j;
    dc += (int)__popcll(mk);
  }
  if (lane == 0) deg[r] = dc;
}

// ---- setup: transpose weights; degree-sort nodes (rank via counting); gather cols by rank
__global__ __launch_bounds__(512) void setup_k(
    const int* __restrict__ deg, const unsigned short* __restrict__ cols,
    const float* __restrict__ W0, const float* __restrict__ W1,
    const float* __restrict__ Wh, int* __restrict__ perm, int* __restrict__ sdeg,
    unsigned short* __restrict__ colsr, float* __restrict__ Wt0,
    float* __restrict__ Wt1, float* __restrict__ Wth) {
  const int tid = threadIdx.x;
  for (int idx = tid; idx < 64 * 64; idx += 512) {
    int d = idx >> 6, c = idx & 63;
    Wt0[c * 64 + d] = W0[idx];
    Wt1[c * 64 + d] = W1[idx];
    Wth[c * 64 + d] = Wh[idx];
  }
  for (int i = tid; i < NN; i += 512) {
    int di = deg[i];
    int r = 0;
    for (int j = 0; j < NN; ++j) {
      int dj = deg[j];
      r += (dj < di) || (dj == di && j < i);
    }
    perm[r] = i;
    sdeg[r] = di;
  }
  __syncthreads();
  for (int idx = tid; idx < NN * (MAXDEG / 2); idx += 512) {
    int r = idx / (MAXDEG / 2), k = idx % (MAXDEG / 2);
    ((unsigned int*)colsr)[idx] =
        ((const unsigned int*)cols)[perm[r] * (MAXDEG / 2) + k];
  }
}

// ---- init: yy=y0, hA = y0@W0, layer-0 scores, head output at t=0 (column-gather W, runs once)
__global__ __launch_bounds__(512) void init_k(
    const float* __restrict__ y0, const float* __restrict__ W0,
    const float* __restrict__ asv, const float* __restrict__ adv,
    const float* __restrict__ Wh, const float* __restrict__ b1v,
    const float* __restrict__ W2v, const float* __restrict__ b2v,
    float* __restrict__ yy, float* __restrict__ hA,
    float* __restrict__ es0, float* __restrict__ ed0, float* __restrict__ out) {
  const int tid = threadIdx.x, lane = tid & 63, wv = tid >> 6;
  const int q = lane & 15;
  const int batch = blockIdx.x & 15, chunk = blockIdx.x >> 4;
  const int n0 = chunk * SLOTS;
  const int cnt = (NN - n0) < SLOTS ? (NN - n0) : SLOTS;
  const int il = wv * 4 + (lane >> 4);
  const int i = n0 + il;
  const bool active = il < cnt;

  float4 x4 = {0.f, 0.f, 0.f, 0.f};
  if (active) {
    x4 = *(const float4*)(y0 + ((size_t)batch * NN + i) * DD + q * 4);
    *(float4*)(yy + ((size_t)batch * NN + i) * DD + q * 4) = x4;
  }

  float wreg[64];
#pragma unroll
  for (int d = 0; d < 64; ++d) wreg[d] = W0[d * 64 + lane];
  float asl = asv[lane], adl = adv[lane];
#pragma unroll
  for (int u2 = 0; u2 < 4; ++u2) {
    int i2l = wv * 4 + u2;
    if (i2l < cnt) {
      int i2 = n0 + i2l;
      float o = 0.f;
#pragma unroll
      for (int dq = 0; dq < 16; ++dq) {
        int sl = (u2 << 4) + dq;
        o = fmaf(rdl(x4.x, sl), wreg[4 * dq + 0], o);
        o = fmaf(rdl(x4.y, sl), wreg[4 * dq + 1], o);
        o = fmaf(rdl(x4.z, sl), wreg[4 * dq + 2], o);
        o = fmaf(rdl(x4.w, sl), wreg[4 * dq + 3], o);
      }
      hA[((size_t)batch * NN + i2) * DD + lane] = o;
      float p = o * asl, qd = o * adl;
#pragma unroll
      for (int mm = 1; mm < 16; mm <<= 1) {
        p += __shfl_xor(p, mm, 64);
        qd += __shfl_xor(qd, mm, 64);
      }
      if ((lane & 15) == 0) {
        es0[((size_t)batch * NN + i2) * 4 + (lane >> 4)] = p;
        ed0[((size_t)batch * NN + i2) * 4 + (lane >> 4)] = qd;
      }
    }
  }
  // head MLP at t=0 on y0
#pragma unroll
  for (int d = 0; d < 64; ++d) wreg[d] = Wh[d * 64 + lane];
  float bb = b1v[lane], w2l = W2v[lane], b2s = b2v[0];
#pragma unroll
  for (int u2 = 0; u2 < 4; ++u2) {
    int i2l = wv * 4 + u2;
    if (i2l < cnt) {
      float o = 0.f;
#pragma unroll
      for (int dq = 0; dq < 16; ++dq) {
        int sl = (u2 << 4) + dq;
        o = fmaf(rdl(x4.x, sl), wreg[4 * dq + 0], o);
        o = fmaf(rdl(x4.y, sl), wreg[4 * dq + 1], o);
        o = fmaf(rdl(x4.z, sl), wreg[4 * dq + 2], o);
        o = fmaf(rdl(x4.w, sl), wreg[4 * dq + 3], o);
      }
      float z = tanhf(o + bb) * w2l;
#pragma unroll
      for (int mm = 1; mm < 64; mm <<= 1) z += __shfl_xor(z, mm, 64);
      if (lane == 0) out[((size_t)batch * (SEQ + 1) + 0) * NN + (n0 + i2l)] = z + b2s;
    }
  }
}

// ---- phase kernel. MODE 0: GAT-layer0 agg -> elu -> @W1 -> h2 + layer1 scores.
//      MODE 1+s: GAT-layer1 agg -> RK stage s -> @W0 -> h1 + layer0 scores (+head at s=3).
// Nodes dealt by degree rank: rank = slot*16 + chunk -> node perm[rank].
// All independent VMEM (W^T, as/ad, yy/acc) issued at kernel top: the
// inter-dispatch L2 invalidate forces these from the MALL (~600-900 cy);
// hoisting hides that under staging+softmax+agg. VGPR ~200 < 256 keeps
// 2 waves/SIMD. MODE 4's Wth load stays late (hoisting both would spill
// past 256 VGPR -> occupancy cliff).
template <int MODE>
__global__ __launch_bounds__(512) void phase_k(
    const float* __restrict__ sin_, float* __restrict__ sout,
    const float* __restrict__ esin, const float* __restrict__ edin,
    float* __restrict__ esout, float* __restrict__ edout,
    const float* __restrict__ Wt, const float* __restrict__ asv,
    const float* __restrict__ adv, const int* __restrict__ permv,
    const int* __restrict__ sdegv, const unsigned short* __restrict__ colsr,
    float* __restrict__ yy, float* __restrict__ acc,
    const float* __restrict__ Wth, const float* __restrict__ b1v,
    const float* __restrict__ W2v, const float* __restrict__ b2v,
    float* __restrict__ out, int tout) {
  __shared__ float slab[NN * SLDS];              // 88.4 KB (XOR-swizzled rows)
  __shared__ float sed[NN * 4];                  // 5.2 KB
  __shared__ float wbuf[SLOTS][4][WPAD];         // 28.2 KB, [slot][head][nbr]
  __shared__ unsigned short jbuf[SLOTS][MAXDEG]; // 3.4 KB

  const int tid = threadIdx.x, lane = tid & 63, wv = tid >> 6;
  const int q = lane & 15, u = lane >> 4, head = q >> 2;
  const int batch = blockIdx.x & 15, chunk = blockIdx.x >> 4;
  const int il = wv * 4 + u;        // slot
  const int rank = il * 16 + chunk; // degree-sorted rank
  const bool active = rank < NN;
  int i = 0, dg = 0;
  if (active) {
    i = permv[rank];
    dg = min(sdegv[rank], MAXDEG);
  }
  float esi = 0.f;
  if (active) esi = esin[((size_t)batch * NN + i) * 4 + (q & 3)];  // hoisted above staging

  // hoisted: W^T column block + score vectors (independent of everything below)
  float wreg[64];
#pragma unroll
  for (int dd = 0; dd < 16; ++dd) {
    float4 v = *(const float4*)(Wt + lane * 64 + dd * 4);
    wreg[4 * dd + 0] = v.x; wreg[4 * dd + 1] = v.y;
    wreg[4 * dd + 2] = v.z; wreg[4 * dd + 3] = v.w;
  }
  const float asl = asv[lane], adl = adv[lane];

  // hoisted: RK state prefetch (written only by PREVIOUS dispatches -> safe)
  float4* accp = nullptr;
  float4* yyp = nullptr;
  float4 yv = {0.f, 0.f, 0.f, 0.f}, av = {0.f, 0.f, 0.f, 0.f};
  if (MODE >= 1 && active) {
    accp = (float4*)(acc + ((size_t)batch * NN + i) * DD + q * 4);
    yyp = (float4*)(yy + ((size_t)batch * NN + i) * DD + q * 4);
    yv = *yyp;
    if (MODE >= 2) av = *accp;
  }

  // stage slab (swizzled) + ed scores + rank-ordered neighbor lists
  const float* sbase = sin_ + (size_t)batch * NN * DD;
  for (int p_ = 0; p_ < 11; ++p_) {
    int r = il + 32 * p_;
    if (r < NN) {
      float4 v = *(const float4*)(sbase + (size_t)r * DD + q * 4);
      *(float4*)&slab[slab_off(r, q)] = v;
    }
  }
  for (int idx = tid; idx < NN * 4; idx += 512) sed[idx] = edin[(size_t)batch * NN * 4 + idx];
  for (int idx = tid; idx < SLOTS * (MAXDEG / 2); idx += 512) {
    int sl_ = idx / (MAXDEG / 2), k = idx % (MAXDEG / 2);
    int rk = sl_ * 16 + chunk;
    if (rk < NN)
      ((unsigned int*)&jbuf[sl_][0])[k] =
          ((const unsigned int*)colsr)[rk * (MAXDEG / 2) + k];
  }
  __syncthreads();

  // softmax weights (no max-subtraction: |e| is O(10), exp safe in fp32)
  if (active) {
    for (int it = 0; it * 4 < dg; ++it) {
      int nbr = it * 4 + (q >> 2);
      if (nbr < dg) {
        int j = jbuf[il][nbr];
        float e = esi + sed[j * 4 + (q & 3)];
        e = fmaxf(e, NEG * e);
        wbuf[il][q & 3][nbr] = __expf(e);
      }
    }
  }
  __builtin_amdgcn_wave_barrier();  // order wave-local LDS writes before reads

  // aggregation: 4 nodes per wave; jbuf/wbuf amortized 4 iters per LDS read
  int dgw = dg;
  dgw = max(dgw, __shfl_xor(dgw, 16, 64));
  dgw = max(dgw, __shfl_xor(dgw, 32, 64));
  const int ilc = active ? il : 0;
  float ax = 0.f, ay = 0.f, az = 0.f, aw = 0.f, den = 0.f;
  const int kch = (dgw + 3) >> 2;
  for (int k = 0; k < kch; ++k) {
    ushort4 j4 = *(const ushort4*)&jbuf[ilc][k * 4];
    v4f w4 = *(const v4f*)&wbuf[ilc][head][k * 4];
#pragma unroll
    for (int m = 0; m < 4; ++m) {
      int jj = k * 4 + m;
      float w = (m == 0) ? w4.x : (m == 1) ? w4.y : (m == 2) ? w4.z : w4.w;
      int j = (m == 0) ? j4.x : (m == 1) ? j4.y : (m == 2) ? j4.z : j4.w;
      if (!(active && jj < dg)) w = 0.f;
      j = j < NN ? j : 0;
      const v4f h = *(const v4f*)&slab[slab_off(j, q)];
      den += w;
      ax = fmaf(w, h.x, ax);
      ay = fmaf(w, h.y, ay);
      az = fmaf(w, h.z, az);
      aw = fmaf(w, h.w, aw);
    }
  }

  float4 x4 = {0.f, 0.f, 0.f, 0.f};
  if (active) {
    float inv = 1.f / den;
    ax *= inv; ay *= inv; az *= inv; aw *= inv;
    if (MODE == 0) {  // elu between GAT layers
      x4.x = ax > 0.f ? ax : __expf(ax) - 1.f;
      x4.y = ay > 0.f ? ay : __expf(ay) - 1.f;
      x4.z = az > 0.f ? az : __expf(az) - 1.f;
      x4.w = aw > 0.f ? aw : __expf(aw) - 1.f;
    } else {
      constexpr int s = MODE - 1;
      if (s == 0) {
        float4 tt; tt.x = ax; tt.y = ay; tt.z = az; tt.w = aw;
        *accp = tt;
        x4.x = yv.x + 0.5f * DT * ax; x4.y = yv.y + 0.5f * DT * ay;
        x4.z = yv.z + 0.5f * DT * az; x4.w = yv.w + 0.5f * DT * aw;
      } else if (s == 1 || s == 2) {
        float4 tt = av;
        tt.x += 2.f * ax; tt.y += 2.f * ay; tt.z += 2.f * az; tt.w += 2.f * aw;
        *accp = tt;
        const float c = (s == 1) ? 0.5f * DT : DT;
        x4.x = yv.x + c * ax; x4.y = yv.y + c * ay;
        x4.z = yv.z + c * az; x4.w = yv.w + c * aw;
      } else {
        x4.x = yv.x + (DT / 6.f) * (av.x + ax);
        x4.y = yv.y + (DT / 6.f) * (av.y + ay);
        x4.z = yv.z + (DT / 6.f) * (av.z + az);
        x4.w = yv.w + (DT / 6.f) * (av.w + aw);
        *yyp = x4;  // y_{t+1}
      }
    }
  }

  // matvec: W^T already in VGPRs; x broadcast via v_readlane
#pragma unroll
  for (int u2 = 0; u2 < 4; ++u2) {
    int rank2 = (wv * 4 + u2) * 16 + chunk;
    if (rank2 < NN) {
      int i2 = permv[rank2];
      float o = 0.f;
#pragma unroll
      for (int dq = 0; dq < 16; ++dq) {
        int sl = (u2 << 4) + dq;
        o = fmaf(rdl(x4.x, sl), wreg[4 * dq + 0], o);
        o = fmaf(rdl(x4.y, sl), wreg[4 * dq + 1], o);
        o = fmaf(rdl(x4.z, sl), wreg[4 * dq + 2], o);
        o = fmaf(rdl(x4.w, sl), wreg[4 * dq + 3], o);
      }
      sout[((size_t)batch * NN + i2) * DD + lane] = o;
      float p = o * asl, qd = o * adl;
#pragma unroll
      for (int mm = 1; mm < 16; mm <<= 1) {
        p += __shfl_xor(p, mm, 64);
        qd += __shfl_xor(qd, mm, 64);
      }
      if ((lane & 15) == 0) {
        esout[((size_t)batch * NN + i2) * 4 + (lane >> 4)] = p;
        edout[((size_t)batch * NN + i2) * 4 + (lane >> 4)] = qd;
      }
    }
  }

  if (MODE == 4) {  // head MLP on fresh y_{t+1} (x4 holds it); Wth loaded late
#pragma unroll
    for (int dd = 0; dd < 16; ++dd) {
      float4 v = *(const float4*)(Wth + lane * 64 + dd * 4);
      wreg[4 * dd + 0] = v.x; wreg[4 * dd + 1] = v.y;
      wreg[4 * dd + 2] = v.z; wreg[4 * dd + 3] = v.w;
    }
    float bb = b1v[lane], w2l = W2v[lane], b2s = b2v[0];
#pragma unroll
    for (int u2 = 0; u2 < 4; ++u2) {
      int rank2 = (wv * 4 + u2) * 16 + chunk;
      if (rank2 < NN) {
        int i2 = permv[rank2];
        float o = 0.f;
#pragma unroll
        for (int dq = 0; dq < 16; ++dq) {
          int sl = (u2 << 4) + dq;
          o = fmaf(rdl(x4.x, sl), wreg[4 * dq + 0], o);
          o = fmaf(rdl(x4.y, sl), wreg[4 * dq + 1], o);
          o = fmaf(rdl(x4.z, sl), wreg[4 * dq + 2], o);
          o = fmaf(rdl(x4.w, sl), wreg[4 * dq + 3], o);
        }
        float z = tanhf(o + bb) * w2l;
#pragma unroll
        for (int mm = 1; mm < 64; mm <<= 1) z += __shfl_xor(z, mm, 64);
        if (lane == 0) out[((size_t)batch * (SEQ + 1) + tout) * NN + i2] = z + b2s;
      }
    }
  }
}

extern "C" void kernel_launch(void* const* d_in, const int* in_sizes, int n_in,
                              void* d_out, int out_size, void* d_ws, size_t ws_size,
                              hipStream_t stream) {
  const float* y0 = (const float*)d_in[0];
  const float* graph = (const float*)d_in[1];
  const float* Wg = (const float*)d_in[2];
  const float* a_src = (const float*)d_in[3];
  const float* a_dst = (const float*)d_in[4];
  const float* W1 = (const float*)d_in[5];
  const float* b1 = (const float*)d_in[6];
  const float* W2 = (const float*)d_in[7];
  const float* b2 = (const float*)d_in[8];
  float* out = (float*)d_out;

  char* ws = (char*)d_ws;
  size_t off = 0;
  auto take = [&](size_t bytes) -> char* {
    char* p = ws + off;
    off += (bytes + 255) & ~size_t(255);
    return p;
  };
  unsigned short* cols = (unsigned short*)take((size_t)NN * MAXDEG * sizeof(unsigned short));
  int* deg = (int*)take(NN * sizeof(int));
  float* hA = (float*)take((size_t)BB * NN * DD * sizeof(float));
  float* hB = (float*)take((size_t)BB * NN * DD * sizeof(float));
  float* es0 = (float*)take((size_t)BB * NN * 4 * sizeof(float));
  float* ed0 = (float*)take((size_t)BB * NN * 4 * sizeof(float));
  float* es1 = (float*)take((size_t)BB * NN * 4 * sizeof(float));
  float* ed1 = (float*)take((size_t)BB * NN * 4 * sizeof(float));
  float* yy = (float*)take((size_t)BB * NN * DD * sizeof(float));
  float* acc = (float*)take((size_t)BB * NN * DD * sizeof(float));
  int* perm = (int*)take(NN * sizeof(int));
  int* sdeg = (int*)take(NN * sizeof(int));
  unsigned short* colsr = (unsigned short*)take((size_t)NN * MAXDEG * sizeof(unsigned short));
  float* Wt0 = (float*)take(64 * 64 * sizeof(float));
  float* Wt1 = (float*)take(64 * 64 * sizeof(float));
  float* Wth = (float*)take(64 * 64 * sizeof(float));
  if (off > ws_size) return;  // loud failure: output stays poisoned

  const float* W0g = Wg;
  const float* W1g = Wg + 64 * 64;
  const dim3 G(256), T(512);

  adj_k<<<dim3(NN), dim3(64), 0, stream>>>(graph, deg, cols);
  setup_k<<<dim3(1), T, 0, stream>>>(deg, cols, W0g, W1g, W1, perm, sdeg, colsr, Wt0, Wt1, Wth);
  init_k<<<G, T, 0, stream>>>(y0, W0g, a_src, a_dst, W1, b1, W2, b2, yy, hA, es0, ed0, out);

  for (int t = 0; t < SEQ; ++t) {
    phase_k<0><<<G, T, 0, stream>>>(hA, hB, es0, ed0, es1, ed1, Wt1, a_src + 64, a_dst + 64,
                                    perm, sdeg, colsr, yy, acc, Wth, b1, W2, b2, out, 0);
    phase_k<1><<<G, T, 0, stream>>>(hB, hA, es1, ed1, es0, ed0, Wt0, a_src, a_dst,
                                    perm, sdeg, colsr, yy, acc, Wth, b1, W2, b2, out, 0);
    phase_k<0><<<G, T, 0, stream>>>(hA, hB, es0, ed0, es1, ed1, Wt1, a_src + 64, a_dst + 64,
                                    perm, sdeg, colsr, yy, acc, Wth, b1, W2, b2, out, 0);
    phase_k<2><<<G, T, 0, stream>>>(hB, hA, es1, ed1, es0, ed0, Wt0, a_src, a_dst,
                                    perm, sdeg, colsr, yy, acc, Wth, b1, W2, b2, out, 0);
    phase_k<0><<<G, T, 0, stream>>>(hA, hB, es0, ed0, es1, ed1, Wt1, a_src + 64, a_dst + 64,
                                    perm, sdeg, colsr, yy, acc, Wth, b1, W2, b2, out, 0);
    phase_k<3><<<G, T, 0, stream>>>(hB, hA, es1, ed1, es0, ed0, Wt0, a_src, a_dst,
                                    perm, sdeg, colsr, yy, acc, Wth, b1, W2, b2, out, 0);
    phase_k<0><<<G, T, 0, stream>>>(hA, hB, es0, ed0, es1, ed1, Wt1, a_src + 64, a_dst + 64,
                                    perm, sdeg, colsr, yy, acc, Wth, b1, W2, b2, out, 0);
    phase_k<4><<<G, T, 0, stream>>>(hB, hA, es1, ed1, es0, ed0, Wt0, a_src, a_dst,
                                    perm, sdeg, colsr, yy, acc, Wth, b1, W2, b2, out, t + 1);
  }
}

// Round 11
// 1141.181 us; speedup vs baseline: 1.3337x; 1.3337x over previous
//
#include <hip/hip_runtime.h>

static constexpr int BB = 16;      // batches
static constexpr int NN = 325;     // nodes
static constexpr int DD = 64;      // channels
static constexpr int SEQ = 12;
static constexpr int MAXDEG = 80;  // per-row cap: Binom(324,0.1) mean 32.4, sd 5.4 -> 8.8 sigma
static constexpr int SLOTS = 21;   // node slots per block (16 blocks x 21 >= 325, round-robin dealt)
static constexpr int SLDS = 68;    // padded slab row stride (dwords); 68*4=272B = 17*16B
static constexpr int WPAD = 84;    // wbuf inner pad (84%32=20 -> conflict-free head rows)
static constexpr float DT = 0.1f;
static constexpr float NEG = 0.2f;
static constexpr float THRESH = 0.9f;

typedef float v4f __attribute__((ext_vector_type(4)));

__device__ __forceinline__ float rdl(float v, int sl) {
  return __int_as_float(__builtin_amdgcn_readlane(__float_as_int(v), sl));
}
// slab swizzle: dword offset within row for channel-quad q (0..15), row r
__device__ __forceinline__ int slab_off(int r, int q) {
  return r * SLDS + ((q ^ ((r >> 3) & 7)) << 2);
}

// ---- adjacency build: one wave per row, ballot compaction; tail zero-filled so
// downstream agg can run branch-free (j=0 is a valid slab row, w=0 kills it)
__global__ __launch_bounds__(64) void adj_k(const float* __restrict__ graph,
                                            int* __restrict__ deg,
                                            unsigned short* __restrict__ cols) {
  const int r = blockIdx.x;
  const int lane = threadIdx.x;
  int dc = 0;
  for (int base = 0; base < NN; base += 64) {
    int j = base + lane;
    bool pred = (j < NN) && ((graph[(size_t)r * NN + j] > THRESH) || (j == r));
    unsigned long long mk = __ballot(pred);
    int pos = dc + (int)__popcll(mk & ((1ULL << lane) - 1ULL));
    if (pred && pos < MAXDEG) cols[(size_t)r * MAXDEG + pos] = (unsigned short)j;
    dc += (int)__popcll(mk);
  }
#pragma unroll
  for (int p = lane; p < MAXDEG; p += 64)
    if (p >= dc) cols[(size_t)r * MAXDEG + p] = 0;
  if (lane == 0) deg[r] = dc;
}

// ---- setup: transpose weights; degree-sort nodes (rank via counting); gather cols by rank
__global__ __launch_bounds__(512) void setup_k(
    const int* __restrict__ deg, const unsigned short* __restrict__ cols,
    const float* __restrict__ W0, const float* __restrict__ W1,
    const float* __restrict__ Wh, int* __restrict__ perm, int* __restrict__ sdeg,
    unsigned short* __restrict__ colsr, float* __restrict__ Wt0,
    float* __restrict__ Wt1, float* __restrict__ Wth) {
  const int tid = threadIdx.x;
  for (int idx = tid; idx < 64 * 64; idx += 512) {
    int d = idx >> 6, c = idx & 63;
    Wt0[c * 64 + d] = W0[idx];
    Wt1[c * 64 + d] = W1[idx];
    Wth[c * 64 + d] = Wh[idx];
  }
  for (int i = tid; i < NN; i += 512) {
    int di = deg[i];
    int r = 0;
    for (int j = 0; j < NN; ++j) {
      int dj = deg[j];
      r += (dj < di) || (dj == di && j < i);
    }
    perm[r] = i;
    sdeg[r] = di;
  }
  __syncthreads();
  for (int idx = tid; idx < NN * (MAXDEG / 2); idx += 512) {
    int r = idx / (MAXDEG / 2), k = idx % (MAXDEG / 2);
    ((unsigned int*)colsr)[idx] =
        ((const unsigned int*)cols)[perm[r] * (MAXDEG / 2) + k];
  }
}

// ---- init: yy=y0, hA = y0@W0, layer-0 scores, head output at t=0 (column-gather W, runs once)
__global__ __launch_bounds__(512) void init_k(
    const float* __restrict__ y0, const float* __restrict__ W0,
    const float* __restrict__ asv, const float* __restrict__ adv,
    const float* __restrict__ Wh, const float* __restrict__ b1v,
    const float* __restrict__ W2v, const float* __restrict__ b2v,
    float* __restrict__ yy, float* __restrict__ hA,
    float* __restrict__ es0, float* __restrict__ ed0, float* __restrict__ out) {
  const int tid = threadIdx.x, lane = tid & 63, wv = tid >> 6;
  const int q = lane & 15;
  const int batch = blockIdx.x & 15, chunk = blockIdx.x >> 4;
  const int n0 = chunk * SLOTS;
  const int cnt = (NN - n0) < SLOTS ? (NN - n0) : SLOTS;
  const int il = wv * 4 + (lane >> 4);
  const int i = n0 + il;
  const bool active = il < cnt;

  float4 x4 = {0.f, 0.f, 0.f, 0.f};
  if (active) {
    x4 = *(const float4*)(y0 + ((size_t)batch * NN + i) * DD + q * 4);
    *(float4*)(yy + ((size_t)batch * NN + i) * DD + q * 4) = x4;
  }

  float wreg[64];
#pragma unroll
  for (int d = 0; d < 64; ++d) wreg[d] = W0[d * 64 + lane];
  float asl = asv[lane], adl = adv[lane];
#pragma unroll
  for (int u2 = 0; u2 < 4; ++u2) {
    int i2l = wv * 4 + u2;
    if (i2l < cnt) {
      int i2 = n0 + i2l;
      float o = 0.f;
#pragma unroll
      for (int dq = 0; dq < 16; ++dq) {
        int sl = (u2 << 4) + dq;
        o = fmaf(rdl(x4.x, sl), wreg[4 * dq + 0], o);
        o = fmaf(rdl(x4.y, sl), wreg[4 * dq + 1], o);
        o = fmaf(rdl(x4.z, sl), wreg[4 * dq + 2], o);
        o = fmaf(rdl(x4.w, sl), wreg[4 * dq + 3], o);
      }
      hA[((size_t)batch * NN + i2) * DD + lane] = o;
      float p = o * asl, qd = o * adl;
#pragma unroll
      for (int mm = 1; mm < 16; mm <<= 1) {
        p += __shfl_xor(p, mm, 64);
        qd += __shfl_xor(qd, mm, 64);
      }
      if ((lane & 15) == 0) {
        es0[((size_t)batch * NN + i2) * 4 + (lane >> 4)] = p;
        ed0[((size_t)batch * NN + i2) * 4 + (lane >> 4)] = qd;
      }
    }
  }
  // head MLP at t=0 on y0
#pragma unroll
  for (int d = 0; d < 64; ++d) wreg[d] = Wh[d * 64 + lane];
  float bb = b1v[lane], w2l = W2v[lane], b2s = b2v[0];
#pragma unroll
  for (int u2 = 0; u2 < 4; ++u2) {
    int i2l = wv * 4 + u2;
    if (i2l < cnt) {
      float o = 0.f;
#pragma unroll
      for (int dq = 0; dq < 16; ++dq) {
        int sl = (u2 << 4) + dq;
        o = fmaf(rdl(x4.x, sl), wreg[4 * dq + 0], o);
        o = fmaf(rdl(x4.y, sl), wreg[4 * dq + 1], o);
        o = fmaf(rdl(x4.z, sl), wreg[4 * dq + 2], o);
        o = fmaf(rdl(x4.w, sl), wreg[4 * dq + 3], o);
      }
      float z = tanhf(o + bb) * w2l;
#pragma unroll
      for (int mm = 1; mm < 64; mm <<= 1) z += __shfl_xor(z, mm, 64);
      if (lane == 0) out[((size_t)batch * (SEQ + 1) + 0) * NN + (n0 + i2l)] = z + b2s;
    }
  }
}

// ---- phase kernel. MODE 0: GAT-layer0 agg -> elu -> @W1 -> h2 + layer1 scores.
//      MODE 1+s: GAT-layer1 agg -> RK stage s -> @W0 -> h1 + layer0 scores (+head at s=3).
// Nodes dealt by degree rank: rank = slot*16 + chunk -> node perm[rank].
// NOTE (round-10 lesson): W^T load stays LATE. Hoisting the 64-VGPR wreg
// above agg stretched its live range across the whole kernel, blew past the
// register budget, and cost +23%. Do not widen wreg's live range.
template <int MODE>
__global__ __launch_bounds__(512) void phase_k(
    const float* __restrict__ sin_, float* __restrict__ sout,
    const float* __restrict__ esin, const float* __restrict__ edin,
    float* __restrict__ esout, float* __restrict__ edout,
    const float* __restrict__ Wt, const float* __restrict__ asv,
    const float* __restrict__ adv, const int* __restrict__ permv,
    const int* __restrict__ sdegv, const unsigned short* __restrict__ colsr,
    float* __restrict__ yy, float* __restrict__ acc,
    const float* __restrict__ Wth, const float* __restrict__ b1v,
    const float* __restrict__ W2v, const float* __restrict__ b2v,
    float* __restrict__ out, int tout) {
  __shared__ float slab[NN * SLDS];              // 88.4 KB (XOR-swizzled rows)
  __shared__ float sed[NN * 4];                  // 5.2 KB
  __shared__ float wbuf[SLOTS][4][WPAD];         // 28.2 KB, [slot][head][nbr]
  __shared__ unsigned short jbuf[SLOTS][MAXDEG]; // 3.4 KB

  const int tid = threadIdx.x, lane = tid & 63, wv = tid >> 6;
  const int q = lane & 15, u = lane >> 4, head = q >> 2;
  const int batch = blockIdx.x & 15, chunk = blockIdx.x >> 4;
  const int il = wv * 4 + u;        // slot
  const int rank = il * 16 + chunk; // degree-sorted rank
  const bool active = rank < NN;
  int i = 0, dg = 0;
  if (active) {
    i = permv[rank];
    dg = min(sdegv[rank], MAXDEG);
  }
  float esi = 0.f;
  if (active) esi = esin[((size_t)batch * NN + i) * 4 + (q & 3)];  // hoisted above staging

  // wave-max padded degree (hoisted: needed by softmax zero-pad AND agg)
  int dgw = dg;
  dgw = max(dgw, __shfl_xor(dgw, 16, 64));
  dgw = max(dgw, __shfl_xor(dgw, 32, 64));
  const int kch = (dgw + 3) >> 2;

  // stage slab (swizzled) + ed scores + rank-ordered neighbor lists
  const float* sbase = sin_ + (size_t)batch * NN * DD;
  for (int p_ = 0; p_ < 11; ++p_) {
    int r = il + 32 * p_;
    if (r < NN) {
      float4 v = *(const float4*)(sbase + (size_t)r * DD + q * 4);
      *(float4*)&slab[slab_off(r, q)] = v;
    }
  }
  for (int idx = tid; idx < NN * 4; idx += 512) sed[idx] = edin[(size_t)batch * NN * 4 + idx];
  for (int idx = tid; idx < SLOTS * (MAXDEG / 2); idx += 512) {
    int sl_ = idx / (MAXDEG / 2), k = idx % (MAXDEG / 2);
    int rk = sl_ * 16 + chunk;
    if (rk < NN)
      ((unsigned int*)&jbuf[sl_][0])[k] =
          ((const unsigned int*)colsr)[rk * (MAXDEG / 2) + k];
  }
  __syncthreads();

  // softmax weights, zero-padded to kch*4 so agg is branch-free.
  // (no max-subtraction: |e| is O(10), exp safe in fp32)
  if (active) {
    for (int it = 0; it < kch; ++it) {
      int nbr = it * 4 + (q >> 2);
      int j = jbuf[il][nbr];  // zero-filled beyond dg (adj_k) -> valid row
      float e = esi + sed[j * 4 + (q & 3)];
      e = fmaxf(e, NEG * e);
      wbuf[il][q & 3][nbr] = (nbr < dg) ? __expf(e) : 0.f;
    }
  }
  __builtin_amdgcn_wave_barrier();  // order wave-local LDS writes before reads

  // aggregation: branch-free (padding has w=0, j=0); jbuf/wbuf amortized
  // 4 iters per LDS read. Inactive lanes compute garbage on slot 0's data
  // but never write (all stores below are active-guarded).
  const int ilc = active ? il : 0;
  float ax = 0.f, ay = 0.f, az = 0.f, aw = 0.f, den = 0.f;
  for (int k = 0; k < kch; ++k) {
    ushort4 j4 = *(const ushort4*)&jbuf[ilc][k * 4];
    v4f w4 = *(const v4f*)&wbuf[ilc][head][k * 4];
#pragma unroll
    for (int m = 0; m < 4; ++m) {
      float w = (m == 0) ? w4.x : (m == 1) ? w4.y : (m == 2) ? w4.z : w4.w;
      int j = (m == 0) ? j4.x : (m == 1) ? j4.y : (m == 2) ? j4.z : j4.w;
      const v4f h = *(const v4f*)&slab[slab_off(j, q)];
      den += w;
      ax = fmaf(w, h.x, ax);
      ay = fmaf(w, h.y, ay);
      az = fmaf(w, h.z, az);
      aw = fmaf(w, h.w, aw);
    }
  }

  float4 x4 = {0.f, 0.f, 0.f, 0.f};
  if (active) {
    float inv = 1.f / den;
    ax *= inv; ay *= inv; az *= inv; aw *= inv;
    if (MODE == 0) {  // elu between GAT layers
      x4.x = ax > 0.f ? ax : __expf(ax) - 1.f;
      x4.y = ay > 0.f ? ay : __expf(ay) - 1.f;
      x4.z = az > 0.f ? az : __expf(az) - 1.f;
      x4.w = aw > 0.f ? aw : __expf(aw) - 1.f;
    } else {
      constexpr int s = MODE - 1;
      float4* accp = (float4*)(acc + ((size_t)batch * NN + i) * DD + q * 4);
      float4* yyp = (float4*)(yy + ((size_t)batch * NN + i) * DD + q * 4);
      float4 yv = *yyp;
      if (s == 0) {
        float4 tt; tt.x = ax; tt.y = ay; tt.z = az; tt.w = aw;
        *accp = tt;
        x4.x = yv.x + 0.5f * DT * ax; x4.y = yv.y + 0.5f * DT * ay;
        x4.z = yv.z + 0.5f * DT * az; x4.w = yv.w + 0.5f * DT * aw;
      } else if (s == 1 || s == 2) {
        float4 tt = *accp;
        tt.x += 2.f * ax; tt.y += 2.f * ay; tt.z += 2.f * az; tt.w += 2.f * aw;
        *accp = tt;
        const float c = (s == 1) ? 0.5f * DT : DT;
        x4.x = yv.x + c * ax; x4.y = yv.y + c * ay;
        x4.z = yv.z + c * az; x4.w = yv.w + c * aw;
      } else {
        float4 tt = *accp;
        x4.x = yv.x + (DT / 6.f) * (tt.x + ax);
        x4.y = yv.y + (DT / 6.f) * (tt.y + ay);
        x4.z = yv.z + (DT / 6.f) * (tt.z + az);
        x4.w = yv.w + (DT / 6.f) * (tt.w + aw);
        *yyp = x4;  // y_{t+1}
      }
    }
  }

  // matvec: W^T rows -> 16 float4 loads/thread (LATE load, see note above)
  float wreg[64];
#pragma unroll
  for (int dd = 0; dd < 16; ++dd) {
    float4 v = *(const float4*)(Wt + lane * 64 + dd * 4);
    wreg[4 * dd + 0] = v.x; wreg[4 * dd + 1] = v.y;
    wreg[4 * dd + 2] = v.z; wreg[4 * dd + 3] = v.w;
  }
  float asl = asv[lane], adl = adv[lane];
#pragma unroll
  for (int u2 = 0; u2 < 4; ++u2) {
    int rank2 = (wv * 4 + u2) * 16 + chunk;
    if (rank2 < NN) {
      int i2 = permv[rank2];
      float o = 0.f;
#pragma unroll
      for (int dq = 0; dq < 16; ++dq) {
        int sl = (u2 << 4) + dq;
        o = fmaf(rdl(x4.x, sl), wreg[4 * dq + 0], o);
        o = fmaf(rdl(x4.y, sl), wreg[4 * dq + 1], o);
        o = fmaf(rdl(x4.z, sl), wreg[4 * dq + 2], o);
        o = fmaf(rdl(x4.w, sl), wreg[4 * dq + 3], o);
      }
      sout[((size_t)batch * NN + i2) * DD + lane] = o;
      float p = o * asl, qd = o * adl;
#pragma unroll
      for (int mm = 1; mm < 16; mm <<= 1) {
        p += __shfl_xor(p, mm, 64);
        qd += __shfl_xor(qd, mm, 64);
      }
      if ((lane & 15) == 0) {
        esout[((size_t)batch * NN + i2) * 4 + (lane >> 4)] = p;
        edout[((size_t)batch * NN + i2) * 4 + (lane >> 4)] = qd;
      }
    }
  }

  if (MODE == 4) {  // head MLP on fresh y_{t+1} (x4 holds it)
#pragma unroll
    for (int dd = 0; dd < 16; ++dd) {
      float4 v = *(const float4*)(Wth + lane * 64 + dd * 4);
      wreg[4 * dd + 0] = v.x; wreg[4 * dd + 1] = v.y;
      wreg[4 * dd + 2] = v.z; wreg[4 * dd + 3] = v.w;
    }
    float bb = b1v[lane], w2l = W2v[lane], b2s = b2v[0];
#pragma unroll
    for (int u2 = 0; u2 < 4; ++u2) {
      int rank2 = (wv * 4 + u2) * 16 + chunk;
      if (rank2 < NN) {
        int i2 = permv[rank2];
        float o = 0.f;
#pragma unroll
        for (int dq = 0; dq < 16; ++dq) {
          int sl = (u2 << 4) + dq;
          o = fmaf(rdl(x4.x, sl), wreg[4 * dq + 0], o);
          o = fmaf(rdl(x4.y, sl), wreg[4 * dq + 1], o);
          o = fmaf(rdl(x4.z, sl), wreg[4 * dq + 2], o);
          o = fmaf(rdl(x4.w, sl), wreg[4 * dq + 3], o);
        }
        float z = tanhf(o + bb) * w2l;
#pragma unroll
        for (int mm = 1; mm < 64; mm <<= 1) z += __shfl_xor(z, mm, 64);
        if (lane == 0) out[((size_t)batch * (SEQ + 1) + tout) * NN + i2] = z + b2s;
      }
    }
  }
}

extern "C" void kernel_launch(void* const* d_in, const int* in_sizes, int n_in,
                              void* d_out, int out_size, void* d_ws, size_t ws_size,
                              hipStream_t stream) {
  const float* y0 = (const float*)d_in[0];
  const float* graph = (const float*)d_in[1];
  const float* Wg = (const float*)d_in[2];
  const float* a_src = (const float*)d_in[3];
  const float* a_dst = (const float*)d_in[4];
  const float* W1 = (const float*)d_in[5];
  const float* b1 = (const float*)d_in[6];
  const float* W2 = (const float*)d_in[7];
  const float* b2 = (const float*)d_in[8];
  float* out = (float*)d_out;

  char* ws = (char*)d_ws;
  size_t off = 0;
  auto take = [&](size_t bytes) -> char* {
    char* p = ws + off;
    off += (bytes + 255) & ~size_t(255);
    return p;
  };
  unsigned short* cols = (unsigned short*)take((size_t)NN * MAXDEG * sizeof(unsigned short));
  int* deg = (int*)take(NN * sizeof(int));
  float* hA = (float*)take((size_t)BB * NN * DD * sizeof(float));
  float* hB = (float*)take((size_t)BB * NN * DD * sizeof(float));
  float* es0 = (float*)take((size_t)BB * NN * 4 * sizeof(float));
  float* ed0 = (float*)take((size_t)BB * NN * 4 * sizeof(float));
  float* es1 = (float*)take((size_t)BB * NN * 4 * sizeof(float));
  float* ed1 = (float*)take((size_t)BB * NN * 4 * sizeof(float));
  float* yy = (float*)take((size_t)BB * NN * DD * sizeof(float));
  float* acc = (float*)take((size_t)BB * NN * DD * sizeof(float));
  int* perm = (int*)take(NN * sizeof(int));
  int* sdeg = (int*)take(NN * sizeof(int));
  unsigned short* colsr = (unsigned short*)take((size_t)NN * MAXDEG * sizeof(unsigned short));
  float* Wt0 = (float*)take(64 * 64 * sizeof(float));
  float* Wt1 = (float*)take(64 * 64 * sizeof(float));
  float* Wth = (float*)take(64 * 64 * sizeof(float));
  if (off > ws_size) return;  // loud failure: output stays poisoned

  const float* W0g = Wg;
  const float* W1g = Wg + 64 * 64;
  const dim3 G(256), T(512);

  adj_k<<<dim3(NN), dim3(64), 0, stream>>>(graph, deg, cols);
  setup_k<<<dim3(1), T, 0, stream>>>(deg, cols, W0g, W1g, W1, perm, sdeg, colsr, Wt0, Wt1, Wth);
  init_k<<<G, T, 0, stream>>>(y0, W0g, a_src, a_dst, W1, b1, W2, b2, yy, hA, es0, ed0, out);

  for (int t = 0; t < SEQ; ++t) {
    phase_k<0><<<G, T, 0, stream>>>(hA, hB, es0, ed0, es1, ed1, Wt1, a_src + 64, a_dst + 64,
                                    perm, sdeg, colsr, yy, acc, Wth, b1, W2, b2, out, 0);
    phase_k<1><<<G, T, 0, stream>>>(hB, hA, es1, ed1, es0, ed0, Wt0, a_src, a_dst,
                                    perm, sdeg, colsr, yy, acc, Wth, b1, W2, b2, out, 0);
    phase_k<0><<<G, T, 0, stream>>>(hA, hB, es0, ed0, es1, ed1, Wt1, a_src + 64, a_dst + 64,
                                    perm, sdeg, colsr, yy, acc, Wth, b1, W2, b2, out, 0);
    phase_k<2><<<G, T, 0, stream>>>(hB, hA, es1, ed1, es0, ed0, Wt0, a_src, a_dst,
                                    perm, sdeg, colsr, yy, acc, Wth, b1, W2, b2, out, 0);
    phase_k<0><<<G, T, 0, stream>>>(hA, hB, es0, ed0, es1, ed1, Wt1, a_src + 64, a_dst + 64,
                                    perm, sdeg, colsr, yy, acc, Wth, b1, W2, b2, out, 0);
    phase_k<3><<<G, T, 0, stream>>>(hB, hA, es1, ed1, es0, ed0, Wt0, a_src, a_dst,
                                    perm, sdeg, colsr, yy, acc, Wth, b1, W2, b2, out, 0);
    phase_k<0><<<G, T, 0, stream>>>(hA, hB, es0, ed0, es1, ed1, Wt1, a_src + 64, a_dst + 64,
                                    perm, sdeg, colsr, yy, acc, Wth, b1, W2, b2, out, 0);
    phase_k<4><<<G, T, 0, stream>>>(hB, hA, es1, ed1, es0, ed0, Wt0, a_src, a_dst,
                                    perm, sdeg, colsr, yy, acc, Wth, b1, W2, b2, out, t + 1);
  }
}

// Round 16
// 1082.493 us; speedup vs baseline: 1.4060x; 1.0542x over previous
//
#include <hip/hip_runtime.h>

static constexpr int BB = 16;      // batches
static constexpr int NN = 325;     // nodes
static constexpr int DD = 64;      // channels
static constexpr int SEQ = 12;
static constexpr int MAXDEG = 80;  // per-row cap: Binom(324,0.1) mean 32.4, sd 5.4 -> 8.8 sigma
static constexpr int SLOTS = 21;   // node slots per block (16 blocks x 21 >= 325, round-robin dealt)
static constexpr int SLDS = 68;    // padded slab row stride (dwords); 68*4=272B = 17*16B
static constexpr int WPAD = 84;    // wbuf inner pad (84%32=20 -> conflict-free head rows)
static constexpr float DT = 0.1f;
static constexpr float NEG = 0.2f;
static constexpr float THRESH = 0.9f;

typedef float v4f __attribute__((ext_vector_type(4)));

__device__ __forceinline__ float rdl(float v, int sl) {
  return __int_as_float(__builtin_amdgcn_readlane(__float_as_int(v), sl));
}
// slab addressing, swizzle-free: a 16-lane q-group reads a FULL row (16
// distinct quads) -> every bank covered exactly 2x (free, m136); the old XOR
// swizzle only permuted lane->quad and could not change the bank multiset.
__device__ __forceinline__ int slab_off(int r, int q) {
  return r * SLDS + (q << 2);
}

// ---- adjacency build: one wave per row, ballot compaction; tail zero-filled so
// downstream agg can run branch-free (j=0 is a valid slab row, w=0 kills it)
__global__ __launch_bounds__(64) void adj_k(const float* __restrict__ graph,
                                            int* __restrict__ deg,
                                            unsigned short* __restrict__ cols) {
  const int r = blockIdx.x;
  const int lane = threadIdx.x;
  int dc = 0;
  for (int base = 0; base < NN; base += 64) {
    int j = base + lane;
    bool pred = (j < NN) && ((graph[(size_t)r * NN + j] > THRESH) || (j == r));
    unsigned long long mk = __ballot(pred);
    int pos = dc + (int)__popcll(mk & ((1ULL << lane) - 1ULL));
    if (pred && pos < MAXDEG) cols[(size_t)r * MAXDEG + pos] = (unsigned short)j;
    dc += (int)__popcll(mk);
  }
#pragma unroll
  for (int p = lane; p < MAXDEG; p += 64)
    if (p >= dc) cols[(size_t)r * MAXDEG + p] = 0;
  if (lane == 0) deg[r] = dc;
}

// ---- setup: transpose weights; degree-sort nodes (rank via counting); gather cols by rank
__global__ __launch_bounds__(512) void setup_k(
    const int* __restrict__ deg, const unsigned short* __restrict__ cols,
    const float* __restrict__ W0, const float* __restrict__ W1,
    const float* __restrict__ Wh, int* __restrict__ perm, int* __restrict__ sdeg,
    unsigned short* __restrict__ colsr, float* __restrict__ Wt0,
    float* __restrict__ Wt1, float* __restrict__ Wth) {
  const int tid = threadIdx.x;
  for (int idx = tid; idx < 64 * 64; idx += 512) {
    int d = idx >> 6, c = idx & 63;
    Wt0[c * 64 + d] = W0[idx];
    Wt1[c * 64 + d] = W1[idx];
    Wth[c * 64 + d] = Wh[idx];
  }
  for (int i = tid; i < NN; i += 512) {
    int di = deg[i];
    int r = 0;
    for (int j = 0; j < NN; ++j) {
      int dj = deg[j];
      r += (dj < di) || (dj == di && j < i);
    }
    perm[r] = i;
    sdeg[r] = di;
  }
  __syncthreads();
  for (int idx = tid; idx < NN * (MAXDEG / 2); idx += 512) {
    int r = idx / (MAXDEG / 2), k = idx % (MAXDEG / 2);
    ((unsigned int*)colsr)[idx] =
        ((const unsigned int*)cols)[perm[r] * (MAXDEG / 2) + k];
  }
}

// ---- init: yy=y0, hA = y0@W0, layer-0 scores, head output at t=0 (column-gather W, runs once)
__global__ __launch_bounds__(512) void init_k(
    const float* __restrict__ y0, const float* __restrict__ W0,
    const float* __restrict__ asv, const float* __restrict__ adv,
    const float* __restrict__ Wh, const float* __restrict__ b1v,
    const float* __restrict__ W2v, const float* __restrict__ b2v,
    float* __restrict__ yy, float* __restrict__ hA,
    float* __restrict__ es0, float* __restrict__ ed0, float* __restrict__ out) {
  const int tid = threadIdx.x, lane = tid & 63, wv = tid >> 6;
  const int q = lane & 15;
  const int batch = blockIdx.x & 15, chunk = blockIdx.x >> 4;
  const int n0 = chunk * SLOTS;
  const int cnt = (NN - n0) < SLOTS ? (NN - n0) : SLOTS;
  const int il = wv * 4 + (lane >> 4);
  const int i = n0 + il;
  const bool active = il < cnt;

  float4 x4 = {0.f, 0.f, 0.f, 0.f};
  if (active) {
    x4 = *(const float4*)(y0 + ((size_t)batch * NN + i) * DD + q * 4);
    *(float4*)(yy + ((size_t)batch * NN + i) * DD + q * 4) = x4;
  }

  float wreg[64];
#pragma unroll
  for (int d = 0; d < 64; ++d) wreg[d] = W0[d * 64 + lane];
  float asl = asv[lane], adl = adv[lane];
#pragma unroll
  for (int u2 = 0; u2 < 4; ++u2) {
    int i2l = wv * 4 + u2;
    if (i2l < cnt) {
      int i2 = n0 + i2l;
      float o = 0.f;
#pragma unroll
      for (int dq = 0; dq < 16; ++dq) {
        int sl = (u2 << 4) + dq;
        o = fmaf(rdl(x4.x, sl), wreg[4 * dq + 0], o);
        o = fmaf(rdl(x4.y, sl), wreg[4 * dq + 1], o);
        o = fmaf(rdl(x4.z, sl), wreg[4 * dq + 2], o);
        o = fmaf(rdl(x4.w, sl), wreg[4 * dq + 3], o);
      }
      hA[((size_t)batch * NN + i2) * DD + lane] = o;
      float p = o * asl, qd = o * adl;
#pragma unroll
      for (int mm = 1; mm < 16; mm <<= 1) {
        p += __shfl_xor(p, mm, 64);
        qd += __shfl_xor(qd, mm, 64);
      }
      if ((lane & 15) == 0) {
        es0[((size_t)batch * NN + i2) * 4 + (lane >> 4)] = p;
        ed0[((size_t)batch * NN + i2) * 4 + (lane >> 4)] = qd;
      }
    }
  }
  // head MLP at t=0 on y0
#pragma unroll
  for (int d = 0; d < 64; ++d) wreg[d] = Wh[d * 64 + lane];
  float bb = b1v[lane], w2l = W2v[lane], b2s = b2v[0];
#pragma unroll
  for (int u2 = 0; u2 < 4; ++u2) {
    int i2l = wv * 4 + u2;
    if (i2l < cnt) {
      float o = 0.f;
#pragma unroll
      for (int dq = 0; dq < 16; ++dq) {
        int sl = (u2 << 4) + dq;
        o = fmaf(rdl(x4.x, sl), wreg[4 * dq + 0], o);
        o = fmaf(rdl(x4.y, sl), wreg[4 * dq + 1], o);
        o = fmaf(rdl(x4.z, sl), wreg[4 * dq + 2], o);
        o = fmaf(rdl(x4.w, sl), wreg[4 * dq + 3], o);
      }
      float z = tanhf(o + bb) * w2l;
#pragma unroll
      for (int mm = 1; mm < 64; mm <<= 1) z += __shfl_xor(z, mm, 64);
      if (lane == 0) out[((size_t)batch * (SEQ + 1) + 0) * NN + (n0 + i2l)] = z + b2s;
    }
  }
}

// ---- phase kernel. MODE 0: GAT-layer0 agg -> elu -> @W1 -> h2 + layer1 scores.
//      MODE 1+s: GAT-layer1 agg -> RK stage s -> @W0 -> h1 + layer0 scores (+head at s=3).
// Nodes dealt by degree rank: rank = slot*16 + chunk -> node perm[rank].
// NOTE (round-10 lesson): W^T load stays LATE; do not widen wreg's live range.
// NOTE (round-15 lesson): x-broadcast uses a DEDICATED xsb[32][64] buffer —
// reusing wbuf aliased/overflowed (il up to 31 > 21 slots) and failed.
template <int MODE>
__global__ __launch_bounds__(512) void phase_k(
    const float* __restrict__ sin_, float* __restrict__ sout,
    const float* __restrict__ esin, const float* __restrict__ edin,
    float* __restrict__ esout, float* __restrict__ edout,
    const float* __restrict__ Wt, const float* __restrict__ asv,
    const float* __restrict__ adv, const int* __restrict__ permv,
    const int* __restrict__ sdegv, const unsigned short* __restrict__ colsr,
    float* __restrict__ yy, float* __restrict__ acc,
    const float* __restrict__ Wth, const float* __restrict__ b1v,
    const float* __restrict__ W2v, const float* __restrict__ b2v,
    float* __restrict__ out, int tout) {
  __shared__ float slab[NN * SLDS];              // 88.4 KB
  __shared__ float sed[NN * 4];                  // 5.2 KB
  __shared__ float wbuf[SLOTS][4][WPAD];         // 28.2 KB, [slot][head][nbr]
  __shared__ unsigned short jbuf[SLOTS][MAXDEG]; // 3.4 KB
  __shared__ float xsb[32][64];                  // 8.0 KB x-broadcast (all il in-bounds)

  const int tid = threadIdx.x, lane = tid & 63, wv = tid >> 6;
  const int q = lane & 15, u = lane >> 4, head = q >> 2;
  const int batch = blockIdx.x & 15, chunk = blockIdx.x >> 4;
  const int il = wv * 4 + u;        // slot
  const int rank = il * 16 + chunk; // degree-sorted rank
  const bool active = rank < NN;
  int i = 0, dg = 0;
  if (active) {
    i = permv[rank];
    dg = min(sdegv[rank], MAXDEG);
  }
  float esi = 0.f;
  if (active) esi = esin[((size_t)batch * NN + i) * 4 + (q & 3)];  // hoisted above staging

  // wave-max padded degree (needed by softmax zero-pad AND agg)
  int dgw = dg;
  dgw = max(dgw, __shfl_xor(dgw, 16, 64));
  dgw = max(dgw, __shfl_xor(dgw, 32, 64));
  const int kch = (dgw + 3) >> 2;

  // stage slab + ed scores + rank-ordered neighbor lists
  const float* sbase = sin_ + (size_t)batch * NN * DD;
  for (int p_ = 0; p_ < 11; ++p_) {
    int r = il + 32 * p_;
    if (r < NN) {
      float4 v = *(const float4*)(sbase + (size_t)r * DD + q * 4);
      *(float4*)&slab[slab_off(r, q)] = v;
    }
  }
  for (int idx = tid; idx < NN * 4; idx += 512) sed[idx] = edin[(size_t)batch * NN * 4 + idx];
  for (int idx = tid; idx < SLOTS * (MAXDEG / 2); idx += 512) {
    int sl_ = idx / (MAXDEG / 2), k = idx % (MAXDEG / 2);
    int rk = sl_ * 16 + chunk;
    if (rk < NN)
      ((unsigned int*)&jbuf[sl_][0])[k] =
          ((const unsigned int*)colsr)[rk * (MAXDEG / 2) + k];
  }
  __syncthreads();

  // softmax weights, zero-padded to kch*4 so agg is branch-free.
  // (no max-subtraction: |e| is O(10), exp safe in fp32)
  if (active) {
    for (int it = 0; it < kch; ++it) {
      int nbr = it * 4 + (q >> 2);
      int j = jbuf[il][nbr];  // zero-filled beyond dg (adj_k) -> valid row
      float e = esi + sed[j * 4 + (q & 3)];
      e = fmaxf(e, NEG * e);
      wbuf[il][q & 3][nbr] = (nbr < dg) ? __expf(e) : 0.f;
    }
  }
  __builtin_amdgcn_wave_barrier();  // order wave-local LDS writes before reads

  // aggregation: branch-free (padding has w=0, j=0); jbuf/wbuf amortized
  // 4 iters per LDS read. Inactive lanes compute garbage on slot 0's data
  // but never write (all stores below are active-guarded).
  const int ilc = active ? il : 0;
  float ax = 0.f, ay = 0.f, az = 0.f, aw = 0.f, den = 0.f;
  for (int k = 0; k < kch; ++k) {
    ushort4 j4 = *(const ushort4*)&jbuf[ilc][k * 4];
    v4f w4 = *(const v4f*)&wbuf[ilc][head][k * 4];
#pragma unroll
    for (int m = 0; m < 4; ++m) {
      float w = (m == 0) ? w4.x : (m == 1) ? w4.y : (m == 2) ? w4.z : w4.w;
      int j = (m == 0) ? j4.x : (m == 1) ? j4.y : (m == 2) ? j4.z : j4.w;
      const v4f h = *(const v4f*)&slab[slab_off(j, q)];
      den += w;
      ax = fmaf(w, h.x, ax);
      ay = fmaf(w, h.y, ay);
      az = fmaf(w, h.z, az);
      aw = fmaf(w, h.w, aw);
    }
  }

  float4 x4 = {0.f, 0.f, 0.f, 0.f};
  if (active) {
    float inv = 1.f / den;
    ax *= inv; ay *= inv; az *= inv; aw *= inv;
    if (MODE == 0) {  // elu between GAT layers
      x4.x = ax > 0.f ? ax : __expf(ax) - 1.f;
      x4.y = ay > 0.f ? ay : __expf(ay) - 1.f;
      x4.z = az > 0.f ? az : __expf(az) - 1.f;
      x4.w = aw > 0.f ? aw : __expf(aw) - 1.f;
    } else {
      constexpr int s = MODE - 1;
      float4* accp = (float4*)(acc + ((size_t)batch * NN + i) * DD + q * 4);
      float4* yyp = (float4*)(yy + ((size_t)batch * NN + i) * DD + q * 4);
      float4 yv = *yyp;
      if (s == 0) {
        float4 tt; tt.x = ax; tt.y = ay; tt.z = az; tt.w = aw;
        *accp = tt;
        x4.x = yv.x + 0.5f * DT * ax; x4.y = yv.y + 0.5f * DT * ay;
        x4.z = yv.z + 0.5f * DT * az; x4.w = yv.w + 0.5f * DT * aw;
      } else if (s == 1 || s == 2) {
        float4 tt = *accp;
        tt.x += 2.f * ax; tt.y += 2.f * ay; tt.z += 2.f * az; tt.w += 2.f * aw;
        *accp = tt;
        const float c = (s == 1) ? 0.5f * DT : DT;
        x4.x = yv.x + c * ax; x4.y = yv.y + c * ay;
        x4.z = yv.z + c * az; x4.w = yv.w + c * aw;
      } else {
        float4 tt = *accp;
        x4.x = yv.x + (DT / 6.f) * (tt.x + ax);
        x4.y = yv.y + (DT / 6.f) * (tt.y + ay);
        x4.z = yv.z + (DT / 6.f) * (tt.z + az);
        x4.w = yv.w + (DT / 6.f) * (tt.w + aw);
        *yyp = x4;  // y_{t+1}
      }
    }
  }

  // publish x4 to the dedicated broadcast buffer. il <= 31 -> always in-bounds;
  // unused slots (inactive groups) hold junk that is never read (reads are
  // rank2<NN-guarded). Intra-wave write->read ordering: LDS ops of a wave are
  // processed in order; wave_barrier pins the compiler schedule.
  *(float4*)&xsb[il][q << 2] = x4;
  __builtin_amdgcn_wave_barrier();

  // matvec: x broadcast via same-address ds_read_b128 (conflict-free);
  // W^T rows -> 16 float4 loads/thread (LATE load, round-10 lesson)
  float wreg[64];
#pragma unroll
  for (int dd = 0; dd < 16; ++dd) {
    float4 v = *(const float4*)(Wt + lane * 64 + dd * 4);
    wreg[4 * dd + 0] = v.x; wreg[4 * dd + 1] = v.y;
    wreg[4 * dd + 2] = v.z; wreg[4 * dd + 3] = v.w;
  }
  float asl = asv[lane], adl = adv[lane];
#pragma unroll
  for (int u2 = 0; u2 < 4; ++u2) {
    int rank2 = (wv * 4 + u2) * 16 + chunk;
    if (rank2 < NN) {
      int i2 = permv[rank2];
      const float* xrow = &xsb[wv * 4 + u2][0];
      float o = 0.f;
#pragma unroll
      for (int dq = 0; dq < 16; ++dq) {
        float4 xv = *(const float4*)&xrow[dq << 2];
        o = fmaf(xv.x, wreg[4 * dq + 0], o);
        o = fmaf(xv.y, wreg[4 * dq + 1], o);
        o = fmaf(xv.z, wreg[4 * dq + 2], o);
        o = fmaf(xv.w, wreg[4 * dq + 3], o);
      }
      sout[((size_t)batch * NN + i2) * DD + lane] = o;
      float p = o * asl, qd = o * adl;
#pragma unroll
      for (int mm = 1; mm < 16; mm <<= 1) {
        p += __shfl_xor(p, mm, 64);
        qd += __shfl_xor(qd, mm, 64);
      }
      if ((lane & 15) == 0) {
        esout[((size_t)batch * NN + i2) * 4 + (lane >> 4)] = p;
        edout[((size_t)batch * NN + i2) * 4 + (lane >> 4)] = qd;
      }
    }
  }

  if (MODE == 4) {  // head MLP on fresh y_{t+1} (xsb still holds it)
#pragma unroll
    for (int dd = 0; dd < 16; ++dd) {
      float4 v = *(const float4*)(Wth + lane * 64 + dd * 4);
      wreg[4 * dd + 0] = v.x; wreg[4 * dd + 1] = v.y;
      wreg[4 * dd + 2] = v.z; wreg[4 * dd + 3] = v.w;
    }
    float bb = b1v[lane], w2l = W2v[lane], b2s = b2v[0];
#pragma unroll
    for (int u2 = 0; u2 < 4; ++u2) {
      int rank2 = (wv * 4 + u2) * 16 + chunk;
      if (rank2 < NN) {
        int i2 = permv[rank2];
        const float* xrow = &xsb[wv * 4 + u2][0];
        float o = 0.f;
#pragma unroll
        for (int dq = 0; dq < 16; ++dq) {
          float4 xv = *(const float4*)&xrow[dq << 2];
          o = fmaf(xv.x, wreg[4 * dq + 0], o);
          o = fmaf(xv.y, wreg[4 * dq + 1], o);
          o = fmaf(xv.z, wreg[4 * dq + 2], o);
          o = fmaf(xv.w, wreg[4 * dq + 3], o);
        }
        float z = tanhf(o + bb) * w2l;
#pragma unroll
        for (int mm = 1; mm < 64; mm <<= 1) z += __shfl_xor(z, mm, 64);
        if (lane == 0) out[((size_t)batch * (SEQ + 1) + tout) * NN + i2] = z + b2s;
      }
    }
  }
}

extern "C" void kernel_launch(void* const* d_in, const int* in_sizes, int n_in,
                              void* d_out, int out_size, void* d_ws, size_t ws_size,
                              hipStream_t stream) {
  const float* y0 = (const float*)d_in[0];
  const float* graph = (const float*)d_in[1];
  const float* Wg = (const float*)d_in[2];
  const float* a_src = (const float*)d_in[3];
  const float* a_dst = (const float*)d_in[4];
  const float* W1 = (const float*)d_in[5];
  const float* b1 = (const float*)d_in[6];
  const float* W2 = (const float*)d_in[7];
  const float* b2 = (const float*)d_in[8];
  float* out = (float*)d_out;

  char* ws = (char*)d_ws;
  size_t off = 0;
  auto take = [&](size_t bytes) -> char* {
    char* p = ws + off;
    off += (bytes + 255) & ~size_t(255);
    return p;
  };
  unsigned short* cols = (unsigned short*)take((size_t)NN * MAXDEG * sizeof(unsigned short));
  int* deg = (int*)take(NN * sizeof(int));
  float* hA = (float*)take((size_t)BB * NN * DD * sizeof(float));
  float* hB = (float*)take((size_t)BB * NN * DD * sizeof(float));
  float* es0 = (float*)take((size_t)BB * NN * 4 * sizeof(float));
  float* ed0 = (float*)take((size_t)BB * NN * 4 * sizeof(float));
  float* es1 = (float*)take((size_t)BB * NN * 4 * sizeof(float));
  float* ed1 = (float*)take((size_t)BB * NN * 4 * sizeof(float));
  float* yy = (float*)take((size_t)BB * NN * DD * sizeof(float));
  float* acc = (float*)take((size_t)BB * NN * DD * sizeof(float));
  int* perm = (int*)take(NN * sizeof(int));
  int* sdeg = (int*)take(NN * sizeof(int));
  unsigned short* colsr = (unsigned short*)take((size_t)NN * MAXDEG * sizeof(unsigned short));
  float* Wt0 = (float*)take(64 * 64 * sizeof(float));
  float* Wt1 = (float*)take(64 * 64 * sizeof(float));
  float* Wth = (float*)take(64 * 64 * sizeof(float));
  if (off > ws_size) return;  // loud failure: output stays poisoned

  const float* W0g = Wg;
  const float* W1g = Wg + 64 * 64;
  const dim3 G(256), T(512);

  adj_k<<<dim3(NN), dim3(64), 0, stream>>>(graph, deg, cols);
  setup_k<<<dim3(1), T, 0, stream>>>(deg, cols, W0g, W1g, W1, perm, sdeg, colsr, Wt0, Wt1, Wth);
  init_k<<<G, T, 0, stream>>>(y0, W0g, a_src, a_dst, W1, b1, W2, b2, yy, hA, es0, ed0, out);

  for (int t = 0; t < SEQ; ++t) {
    phase_k<0><<<G, T, 0, stream>>>(hA, hB, es0, ed0, es1, ed1, Wt1, a_src + 64, a_dst + 64,
                                    perm, sdeg, colsr, yy, acc, Wth, b1, W2, b2, out, 0);
    phase_k<1><<<G, T, 0, stream>>>(hB, hA, es1, ed1, es0, ed0, Wt0, a_src, a_dst,
                                    perm, sdeg, colsr, yy, acc, Wth, b1, W2, b2, out, 0);
    phase_k<0><<<G, T, 0, stream>>>(hA, hB, es0, ed0, es1, ed1, Wt1, a_src + 64, a_dst + 64,
                                    perm, sdeg, colsr, yy, acc, Wth, b1, W2, b2, out, 0);
    phase_k<2><<<G, T, 0, stream>>>(hB, hA, es1, ed1, es0, ed0, Wt0, a_src, a_dst,
                                    perm, sdeg, colsr, yy, acc, Wth, b1, W2, b2, out, 0);
    phase_k<0><<<G, T, 0, stream>>>(hA, hB, es0, ed0, es1, ed1, Wt1, a_src + 64, a_dst + 64,
                                    perm, sdeg, colsr, yy, acc, Wth, b1, W2, b2, out, 0);
    phase_k<3><<<G, T, 0, stream>>>(hB, hA, es1, ed1, es0, ed0, Wt0, a_src, a_dst,
                                    perm, sdeg, colsr, yy, acc, Wth, b1, W2, b2, out, 0);
    phase_k<0><<<G, T, 0, stream>>>(hA, hB, es0, ed0, es1, ed1, Wt1, a_src + 64, a_dst + 64,
                                    perm, sdeg, colsr, yy, acc, Wth, b1, W2, b2, out, 0);
    phase_k<4><<<G, T, 0, stream>>>(hB, hA, es1, ed1, es0, ed0, Wt0, a_src, a_dst,
                                    perm, sdeg, colsr, yy, acc, Wth, b1, W2, b2, out, t + 1);
  }
}